// Round 9
// baseline (237.196 us; speedup 1.0000x reference)
//
#include <hip/hip_runtime.h>
#include <cstddef>

#define BB 8
#define SS 2048
#define DD 512
#define MM (BB * SS)

typedef __attribute__((ext_vector_type(8))) short bf16x8;
typedef __attribute__((ext_vector_type(4))) float f32x4;
typedef __attribute__((ext_vector_type(4))) unsigned short u16x4;

__device__ __forceinline__ f32x4 mfma16(bf16x8 a, bf16x8 b, f32x4 c) {
  return __builtin_amdgcn_mfma_f32_16x16x32_bf16(a, b, c, 0, 0, 0);
}
__device__ __forceinline__ unsigned short f2bf(float f) {
  unsigned int u = __float_as_uint(f);
  u += 0x7fffu + ((u >> 16) & 1u);
  return (unsigned short)(u >> 16);
}
__device__ __forceinline__ void gld16(const void* g, void* l) {
  __builtin_amdgcn_global_load_lds((const __attribute__((address_space(1))) void*)g,
                                   (__attribute__((address_space(3))) void*)l, 16, 0, 0);
}

// ---------------- merged prep: x->bf16 (8192 blocks), W3->bf16 (768), mask scan (8) ----
__global__ void prep_kernel(const float* __restrict__ x, unsigned short* __restrict__ Xb,
                            const float* __restrict__ Wq, const float* __restrict__ Wk,
                            const float* __restrict__ Wv, unsigned short* __restrict__ Wqb,
                            unsigned short* __restrict__ Wkb, unsigned short* __restrict__ Wvb,
                            const int* __restrict__ mask, int* __restrict__ idx,
                            int* __restrict__ nbArr) {
  __shared__ int part[256];
  const int bx = blockIdx.x;
  const int t = threadIdx.x;
  if (bx < 8192) {  // x conversion: 8192*256 f32x4 = MM*DD
    const int i = bx * 256 + t;
    f32x4 v = reinterpret_cast<const f32x4*>(x)[i];
    u16x4 o;
    o[0] = f2bf(v[0]);
    o[1] = f2bf(v[1]);
    o[2] = f2bf(v[2]);
    o[3] = f2bf(v[3]);
    reinterpret_cast<u16x4*>(Xb)[i] = o;
    return;
  }
  if (bx < 8960) {  // weights: 256 blocks per matrix
    const int k = bx - 8192;
    const int which = k >> 8;
    const float* s = which == 0 ? Wq : (which == 1 ? Wk : Wv);
    unsigned short* d = which == 0 ? Wqb : (which == 1 ? Wkb : Wvb);
    const int i = (k & 255) * 256 + t;
    f32x4 v = reinterpret_cast<const f32x4*>(s)[i];
    u16x4 o;
    o[0] = f2bf(v[0]);
    o[1] = f2bf(v[1]);
    o[2] = f2bf(v[2]);
    o[3] = f2bf(v[3]);
    reinterpret_cast<u16x4*>(d)[i] = o;
    return;
  }
  // ---- mask scan: active-key index list (tail zeroed), b = bx - 8960 ----
  const int b = bx - 8960;
  int m[8], c = 0;
#pragma unroll
  for (int e = 0; e < 8; ++e) {
    m[e] = mask[b * SS + t * 8 + e];
    c += (m[e] != 0);
  }
  int v = c;
  part[t] = v;
  __syncthreads();
  for (int off = 1; off < 256; off <<= 1) {
    int u = (t >= off) ? part[t - off] : 0;
    __syncthreads();
    v += u;
    part[t] = v;
    __syncthreads();
  }
  int base = v - c;
#pragma unroll
  for (int e = 0; e < 8; ++e)
    if (m[e]) idx[b * SS + base++] = t * 8 + e;
  const int nb = part[255];
  if (t == 255) nbArr[b] = nb;
  for (int j = nb + t; j < SS; j += 256) idx[b * SS + j] = 0;
}

// ---------------- fused QKV GEMM: 256x256 tile, BK=64, 2-phase prefetch ------
// 512 threads / 8 waves (2M x 4N, 128x64 per wave), double-buffered 128KB LDS
// (1 block/CU), T3-minimum pipeline: stage(t+1) -> compute(t) -> vmcnt(0)+bar.
// Same chunk^(row&7) both-sides swizzle as the proven 128^2 kernel. Grid 384:
// bid = xcd + 8*(nI + 6*mhi) puts the 6 blocks sharing an A-panel on ONE XCD.
// Q output pre-scaled by 1/sqrt(512).
__global__ __launch_bounds__(512, 2) void qkv_gemm_kernel(
    const unsigned short* __restrict__ X, const unsigned short* __restrict__ W0,
    const unsigned short* __restrict__ W1, const unsigned short* __restrict__ W2,
    const float* __restrict__ b0, const float* __restrict__ b1,
    const float* __restrict__ b2, unsigned short* __restrict__ O0,
    unsigned short* __restrict__ O1, unsigned short* __restrict__ O2) {
  __shared__ unsigned char a_lds[2][32 * 1024];
  __shared__ unsigned char b_lds[2][32 * 1024];
  const int tid = threadIdx.x;
  const int w = tid >> 6, l = tid & 63, lr = l & 15, hi = l >> 4;
  // grid decode (XCD-affinity for A-panel reuse)
  const int bid = blockIdx.x;
  const int xcd = bid & 7;
  const int q = bid >> 3;       // [0,48)
  const int nI = q % 6;         // n-tile of 256
  const int mhi = q / 6;        // [0,8)
  const int mI = mhi * 8 + xcd; // m-tile of 256
  const int which = nI >> 1;
  const unsigned short* W = which == 0 ? W0 : (which == 1 ? W1 : W2);
  const float* bias = which == 0 ? b0 : (which == 1 ? b1 : b2);
  unsigned short* out = which == 0 ? O0 : (which == 1 ? O1 : O2);
  const float oscale = which == 0 ? 0.044194173824159216f : 1.0f;
  const int m0 = mI * 256;
  const int nc0 = (nI & 1) * 256;  // col base within the selected matrix
  const int wm = (w >> 2) * 128, wn = (w & 3) * 64;
  const int srow = l >> 3, gchunk = (l & 7) ^ (srow & 7);

  f32x4 acc[8][4];
#pragma unroll
  for (int mt = 0; mt < 8; ++mt)
#pragma unroll
    for (int nt = 0; nt < 4; ++nt) acc[mt][nt] = (f32x4){0.f, 0.f, 0.f, 0.f};

  // wave w stages rows w*32 .. w*32+31 of A and B tiles (4 gld16 each)
  const unsigned short* ga = X + (size_t)(m0 + w * 32 + srow) * DD + gchunk * 8;
  const unsigned short* gb = W + (size_t)(nc0 + w * 32 + srow) * DD + gchunk * 8;

  auto stage = [&](int k0, int buf) {
#pragma unroll
    for (int ii = 0; ii < 4; ++ii) {
      gld16(ga + (size_t)ii * 8 * DD + k0, &a_lds[buf][(w * 4 + ii) * 1024]);
      gld16(gb + (size_t)ii * 8 * DD + k0, &b_lds[buf][(w * 4 + ii) * 1024]);
    }
  };
  auto compute = [&](int buf) {
#pragma unroll
    for (int dkl = 0; dkl < 2; ++dkl) {
      const int gc = dkl * 4 + hi;
      bf16x8 af[8], bfr[4];
#pragma unroll
      for (int mt = 0; mt < 8; ++mt) {
        const int row = wm + mt * 16 + lr;
        af[mt] = *reinterpret_cast<const bf16x8*>(
            &a_lds[buf][row * 128 + ((gc ^ (row & 7)) * 16)]);
      }
#pragma unroll
      for (int nt = 0; nt < 4; ++nt) {
        const int row = wn + nt * 16 + lr;
        bfr[nt] = *reinterpret_cast<const bf16x8*>(
            &b_lds[buf][row * 128 + ((gc ^ (row & 7)) * 16)]);
      }
#pragma unroll
      for (int mt = 0; mt < 8; ++mt)
#pragma unroll
        for (int nt = 0; nt < 4; ++nt)
          acc[mt][nt] = mfma16(af[mt], bfr[nt], acc[mt][nt]);
    }
  };

  stage(0, 0);
  asm volatile("s_waitcnt vmcnt(0)" ::: "memory");
  __builtin_amdgcn_s_barrier();
  int cur = 0;
  for (int ks = 0; ks < (DD / 64) - 1; ++ks) {
    stage((ks + 1) * 64, cur ^ 1);  // prefetch next K-slab
    compute(cur);                   // hides the staging latency
    asm volatile("s_waitcnt vmcnt(0)" ::: "memory");
    __builtin_amdgcn_s_barrier();
    cur ^= 1;
  }
  compute(cur);

#pragma unroll
  for (int nt = 0; nt < 4; ++nt) {
    const int col = nc0 + wn + nt * 16 + lr;
    const float bv = bias[col];
#pragma unroll
    for (int mt = 0; mt < 8; ++mt)
#pragma unroll
      for (int r = 0; r < 4; ++r) {
        const int row = m0 + wm + mt * 16 + hi * 4 + r;
        out[(size_t)row * DD + col] = f2bf((acc[mt][nt][r] + bv) * oscale);
      }
  }
}

// ---------------- V gather+tiled-transpose ----------------
// VT2[b][kt64][cc][d][jj] = Vc[b][kt64*64 + cc*8 + jj][d]
__global__ void vtrans_kernel(const unsigned short* __restrict__ V,
                              const int* __restrict__ idx, const int* __restrict__ nbArr,
                              unsigned short* __restrict__ VT2) {
  __shared__ unsigned short t[64][72];
  const int b = blockIdx.z;
  const int kt = blockIdx.x;
  const int d0 = blockIdx.y * 64;
  const int tid = threadIdx.x;
  const int c = tid & 63, rg = tid >> 6;
  const int nb = nbArr[b];
#pragma unroll
  for (int i = 0; i < 16; ++i) {
    const int row = rg * 16 + i;
    const int s = kt * 64 + row;
    const int src = s < nb ? idx[b * SS + s] : 0;
    t[row][c] = V[((size_t)b * SS + src) * DD + d0 + c];
  }
  __syncthreads();
#pragma unroll
  for (int i = 0; i < 16; ++i) {
    const int ix = i * 256 + tid;
    const int jj = ix & 7;
    const int dl = (ix >> 3) & 63;
    const int cc = ix >> 9;
    VT2[(((size_t)(b * 32 + kt) * 8 + cc) * 512 + d0 + dl) * 8 + jj] =
        t[cc * 8 + jj][dl];
  }
}

// ---------------- flash attention: R6 structure + T5 setprio (R8-proven) ----
__global__ __launch_bounds__(256, 2) void attn_kernel(
    const unsigned short* __restrict__ Q, const unsigned short* __restrict__ K,
    const unsigned short* __restrict__ VT2, const int* __restrict__ idx,
    const int* __restrict__ nbArr, float* __restrict__ Out,
    float* __restrict__ Apart, float* __restrict__ mlpart) {
  __shared__ unsigned char k_lds[32 * 1024];      // swizzled K tile
  __shared__ unsigned char vt_lds[4 * 512 * 16];  // [cc][d][8 keys]
  __shared__ unsigned short pbuf[4][16][32];
  __shared__ int ids[1024];
  const int tid = threadIdx.x;
  const int w = tid >> 6, l = tid & 63, lr = l & 15, hi = l >> 4;
  const int bid = blockIdx.x;
  const int b = bid & 7;  // XCD-affinity
  const int qt = (bid >> 3) >> 1;
  const int sp = (bid >> 3) & 1;
  const int q0 = qt * 64 + w * 16;

  const int nb = nbArr[b];
  const int ntile = (nb + 31) >> 5;
  const int half = (ntile + 1) >> 1;
  const int lo = sp == 0 ? 0 : half;
  const int hi_t = sp == 0 ? half : ntile;
  const int ntl = hi_t - lo;

  const unsigned short* __restrict__ Qb = Q + (size_t)b * SS * DD;
  const unsigned short* __restrict__ Kb = K + (size_t)b * SS * DD;
  const unsigned short* __restrict__ Vb = VT2 + (size_t)b * SS * DD;
  const int* __restrict__ idxb = idx + b * SS;

  for (int j = tid; j < ntl * 32; j += 256) ids[j] = idxb[lo * 32 + j];

  bf16x8 qf[16];
#pragma unroll
  for (int dk = 0; dk < 16; ++dk)
    qf[dk] = *reinterpret_cast<const bf16x8*>(
        &Qb[(size_t)(q0 + lr) * DD + dk * 32 + hi * 8]);

  f32x4 oacc[32];
#pragma unroll
  for (int i = 0; i < 32; ++i) oacc[i] = (f32x4){0.f, 0.f, 0.f, 0.f};
  float mrow[4], lrow[4];
#pragma unroll
  for (int r = 0; r < 4; ++r) {
    mrow[r] = -10000.0f;
    lrow[r] = 0.0f;
  }

  __syncthreads();  // ids visible

  for (int t = lo; t < hi_t; ++t) {
    const int tr = t - lo;
    // ---- issue K loads first (oldest 8 per lane) ----
#pragma unroll
    for (int r = 0; r < 8; ++r) {
      const int row = w * 8 + r;
      const int src = ids[tr * 32 + row];
      const int ch = (l & 56) | ((l ^ row) & 7);
      gld16(Kb + (size_t)src * DD + ch * 8, &k_lds[row * 1024]);
    }
    // ---- then V loads (youngest 8 per lane) ----
    const size_t vbase = ((size_t)((t >> 1) * 8 + (t & 1) * 4 + w) * 512);
#pragma unroll
    for (int g = 0; g < 8; ++g)
      gld16(Vb + (vbase + g * 64 + l) * 8, &vt_lds[(w * 512 + g * 64) * 16]);

    // ---- K landed (V still in flight) ----
    asm volatile("s_waitcnt vmcnt(8)" ::: "memory");
    __builtin_amdgcn_s_barrier();

    // ---- S = Q @ K^T (32 keys); Q pre-scaled ----
    f32x4 sacc[2];
#pragma unroll
    for (int nt = 0; nt < 2; ++nt) sacc[nt] = (f32x4){0.f, 0.f, 0.f, 0.f};
    __builtin_amdgcn_s_setprio(1);
#pragma unroll
    for (int dk = 0; dk < 16; ++dk) {
#pragma unroll
      for (int nt = 0; nt < 2; ++nt) {
        const int row = nt * 16 + lr;
        const int c = dk * 4 + hi;
        bf16x8 bk = *reinterpret_cast<const bf16x8*>(
            &k_lds[row * 1024 + ((c & ~7) | ((c ^ row) & 7)) * 16]);
        sacc[nt] = mfma16(qf[dk], bk, sacc[nt]);
      }
    }
    __builtin_amdgcn_s_setprio(0);

    float s[2][4];
#pragma unroll
    for (int nt = 0; nt < 2; ++nt) {
      const int j = t * 32 + nt * 16 + lr;
      const bool ok = j < nb;
#pragma unroll
      for (int r = 0; r < 4; ++r)
        s[nt][r] = ok ? sacc[nt][r] : -10000.0f;
    }

    // ---- online softmax with defer-max (T13, THR=8) ----
    float mx[4];
    float need = -1e30f;
#pragma unroll
    for (int r = 0; r < 4; ++r) {
      float m2 = fmaxf(s[0][r], s[1][r]);
#pragma unroll
      for (int off = 1; off < 16; off <<= 1) m2 = fmaxf(m2, __shfl_xor(m2, off));
      mx[r] = m2;
      need = fmaxf(need, m2 - mrow[r]);
    }
    if (__any(need > 8.0f)) {
#pragma unroll
      for (int r = 0; r < 4; ++r) {
        const float mnew = fmaxf(mrow[r], mx[r]);
        const float alpha = __expf(mrow[r] - mnew);
        mrow[r] = mnew;
        lrow[r] *= alpha;
#pragma unroll
        for (int nt2 = 0; nt2 < 32; ++nt2) oacc[nt2][r] *= alpha;
      }
    }
    float rs[4] = {0.f, 0.f, 0.f, 0.f};
#pragma unroll
    for (int nt = 0; nt < 2; ++nt)
#pragma unroll
      for (int r = 0; r < 4; ++r) {
        float p = __expf(s[nt][r] - mrow[r]);
        s[nt][r] = p;
        rs[r] += p;
      }
#pragma unroll
    for (int r = 0; r < 4; ++r) {
      float tt = rs[r];
#pragma unroll
      for (int off = 1; off < 16; off <<= 1) tt += __shfl_xor(tt, off);
      lrow[r] += tt;
    }

    // ---- P relayout C->A via per-wave LDS ----
#pragma unroll
    for (int nt = 0; nt < 2; ++nt)
#pragma unroll
      for (int r = 0; r < 4; ++r)
        pbuf[w][hi * 4 + r][nt * 16 + lr] = f2bf(s[nt][r]);
    bf16x8 pf = *reinterpret_cast<const bf16x8*>(&pbuf[w][lr][hi * 8]);

    // ---- V landed for all waves ----
    asm volatile("s_waitcnt vmcnt(0)" ::: "memory");
    __builtin_amdgcn_s_barrier();

    // ---- O += P @ V from LDS ----
    __builtin_amdgcn_s_setprio(1);
#pragma unroll
    for (int nt2 = 0; nt2 < 32; ++nt2) {
      bf16x8 v0 = *reinterpret_cast<const bf16x8*>(
          &vt_lds[(hi * 512 + nt2 * 16 + lr) * 16]);
      oacc[nt2] = mfma16(pf, v0, oacc[nt2]);
    }
    __builtin_amdgcn_s_setprio(0);
    __syncthreads();  // all PV reads done before next tile's staging
  }

  float* Ap = sp == 0 ? Out : Apart;
#pragma unroll
  for (int nt2 = 0; nt2 < 32; ++nt2)
#pragma unroll
    for (int r = 0; r < 4; ++r)
      Ap[((size_t)b * SS + q0 + hi * 4 + r) * DD + nt2 * 16 + lr] = oacc[nt2][r];
  if (lr == 0) {
#pragma unroll
    for (int r = 0; r < 4; ++r) {
      const size_t row = (size_t)sp * MM + b * SS + q0 + hi * 4 + r;
      mlpart[row * 2 + 0] = mrow[r];
      mlpart[row * 2 + 1] = lrow[r];
    }
  }
}

// ---------------- combine: in-place merge split0 (in Out) + split1 (Apart) ----------------
__global__ void combine_kernel(float* __restrict__ Out, const float* __restrict__ Apart,
                               const float* __restrict__ mlpart) {
  const int gid = blockIdx.x * 256 + threadIdx.x;  // over MM*DD/4
  const int row = gid >> 7;
  const float m1 = mlpart[(size_t)row * 2 + 0];
  const float l1 = mlpart[(size_t)row * 2 + 1];
  const float m2 = mlpart[((size_t)MM + row) * 2 + 0];
  const float l2 = mlpart[((size_t)MM + row) * 2 + 1];
  const float m = fmaxf(m1, m2);
  const float w1 = __expf(m1 - m), w2 = __expf(m2 - m);
  const float inv = 1.0f / (w1 * l1 + w2 * l2);
  f32x4 a1 = reinterpret_cast<f32x4*>(Out)[gid];
  f32x4 a2 = reinterpret_cast<const f32x4*>(Apart)[gid];
  f32x4 o;
#pragma unroll
  for (int e = 0; e < 4; ++e) o[e] = (w1 * a1[e] + w2 * a2[e]) * inv;
  reinterpret_cast<f32x4*>(Out)[gid] = o;
}

extern "C" void kernel_launch(void* const* d_in, const int* in_sizes, int n_in,
                              void* d_out, int out_size, void* d_ws, size_t ws_size,
                              hipStream_t stream) {
  const float* x = (const float*)d_in[0];
  const int* mask = (const int*)d_in[1];
  const float* Wq = (const float*)d_in[2];
  const float* bq = (const float*)d_in[3];
  const float* Wk = (const float*)d_in[4];
  const float* bk = (const float*)d_in[5];
  const float* Wv = (const float*)d_in[6];
  const float* bv = (const float*)d_in[7];
  float* out = (float*)d_out;

  // ws layout (max ~82.4 MB, R4-proven):
  //   0-16   Qb          (live through attn)
  //   16-32  Kb          (live through attn)
  //   32-48  VT2b        (live through attn)
  //   48-64  Xb          (dead after qkv_gemm)
  //   64-80  Vb          (dead after vtrans)
  //   48-80  Apart       (split1 partial, 32 MB — aliases Xb+Vb, both dead)
  //   80-81.5 weights    (dead after qkv_gemm)
  //   82+    idx (64KB), nbArr, mlpart (256KB)
  char* ws = (char*)d_ws;
  const size_t MB = 1024 * 1024;
  unsigned short* Qb = (unsigned short*)(ws);
  unsigned short* Kb = (unsigned short*)(ws + 16 * MB);
  unsigned short* VT2b = (unsigned short*)(ws + 32 * MB);
  unsigned short* Xb = (unsigned short*)(ws + 48 * MB);
  unsigned short* Vb = (unsigned short*)(ws + 64 * MB);
  float* Apart = (float*)(ws + 48 * MB);
  unsigned short* Wqb = (unsigned short*)(ws + 80 * MB);
  unsigned short* Wkb = Wqb + 512 * 512;
  unsigned short* Wvb = Wkb + 512 * 512;
  int* idx = (int*)(ws + 82 * MB);
  int* nbArr = (int*)(ws + 82 * MB + 65536);
  float* mlpart = (float*)(ws + 82 * MB + 128 * 1024);

  prep_kernel<<<8968, 256, 0, stream>>>(x, Xb, Wq, Wk, Wv, Wqb, Wkb, Wvb, mask, idx,
                                        nbArr);

  qkv_gemm_kernel<<<384, 512, 0, stream>>>(Xb, Wqb, Wkb, Wvb, bq, bk, bv, Qb, Kb, Vb);

  vtrans_kernel<<<dim3(SS / 64, DD / 64, BB), 256, 0, stream>>>(Vb, idx, nbArr, VT2b);

  attn_kernel<<<512, 256, 0, stream>>>(Qb, Kb, VT2b, idx, nbArr, out, Apart, mlpart);

  combine_kernel<<<(MM * DD / 4) / 256, 256, 0, stream>>>(out, Apart, mlpart);
}

// Round 11
// 228.122 us; speedup vs baseline: 1.0398x; 1.0398x over previous
//
#include <hip/hip_runtime.h>
#include <cstddef>

#define BB 8
#define SS 2048
#define DD 512
#define MM (BB * SS)

typedef __attribute__((ext_vector_type(8))) short bf16x8;
typedef __attribute__((ext_vector_type(4))) float f32x4;
typedef __attribute__((ext_vector_type(4))) unsigned short u16x4;

__device__ __forceinline__ f32x4 mfma16(bf16x8 a, bf16x8 b, f32x4 c) {
  return __builtin_amdgcn_mfma_f32_16x16x32_bf16(a, b, c, 0, 0, 0);
}
__device__ __forceinline__ unsigned short f2bf(float f) {
  unsigned int u = __float_as_uint(f);
  u += 0x7fffu + ((u >> 16) & 1u);
  return (unsigned short)(u >> 16);
}
__device__ __forceinline__ void gld16(const void* g, void* l) {
  __builtin_amdgcn_global_load_lds((const __attribute__((address_space(1))) void*)g,
                                   (__attribute__((address_space(3))) void*)l, 16, 0, 0);
}

// ---------------- merged prep: x->bf16 (8192 blocks), W3->bf16 (768), mask scan (8) ----
__global__ void prep_kernel(const float* __restrict__ x, unsigned short* __restrict__ Xb,
                            const float* __restrict__ Wq, const float* __restrict__ Wk,
                            const float* __restrict__ Wv, unsigned short* __restrict__ Wqb,
                            unsigned short* __restrict__ Wkb, unsigned short* __restrict__ Wvb,
                            const int* __restrict__ mask, int* __restrict__ idx,
                            int* __restrict__ nbArr) {
  __shared__ int part[256];
  const int bx = blockIdx.x;
  const int t = threadIdx.x;
  if (bx < 8192) {  // x conversion: 8192*256 f32x4 = MM*DD
    const int i = bx * 256 + t;
    f32x4 v = reinterpret_cast<const f32x4*>(x)[i];
    u16x4 o;
    o[0] = f2bf(v[0]);
    o[1] = f2bf(v[1]);
    o[2] = f2bf(v[2]);
    o[3] = f2bf(v[3]);
    reinterpret_cast<u16x4*>(Xb)[i] = o;
    return;
  }
  if (bx < 8960) {  // weights: 256 blocks per matrix
    const int k = bx - 8192;
    const int which = k >> 8;
    const float* s = which == 0 ? Wq : (which == 1 ? Wk : Wv);
    unsigned short* d = which == 0 ? Wqb : (which == 1 ? Wkb : Wvb);
    const int i = (k & 255) * 256 + t;
    f32x4 v = reinterpret_cast<const f32x4*>(s)[i];
    u16x4 o;
    o[0] = f2bf(v[0]);
    o[1] = f2bf(v[1]);
    o[2] = f2bf(v[2]);
    o[3] = f2bf(v[3]);
    reinterpret_cast<u16x4*>(d)[i] = o;
    return;
  }
  // ---- mask scan: active-key index list (tail zeroed), b = bx - 8960 ----
  const int b = bx - 8960;
  int m[8], c = 0;
#pragma unroll
  for (int e = 0; e < 8; ++e) {
    m[e] = mask[b * SS + t * 8 + e];
    c += (m[e] != 0);
  }
  int v = c;
  part[t] = v;
  __syncthreads();
  for (int off = 1; off < 256; off <<= 1) {
    int u = (t >= off) ? part[t - off] : 0;
    __syncthreads();
    v += u;
    part[t] = v;
    __syncthreads();
  }
  int base = v - c;
#pragma unroll
  for (int e = 0; e < 8; ++e)
    if (m[e]) idx[b * SS + base++] = t * 8 + e;
  const int nb = part[255];
  if (t == 255) nbArr[b] = nb;
  for (int j = nb + t; j < SS; j += 256) idx[b * SS + j] = 0;
}

// ---------------- fused QKV GEMM, BK=128, XCD-affinity swizzle (R8-proven) ----
// Flat grid 1536; bid = (m0>>3)*96 + j*8 + (m0&7) so the 12 (which,n0) blocks
// sharing an A-tile are 8 apart -> same XCD -> A-tile read once into that L2.
// Q output is pre-scaled by 1/sqrt(512) so attn skips the per-tile multiply.
__global__ __launch_bounds__(256, 2) void qkv_gemm_kernel(
    const unsigned short* __restrict__ X, const unsigned short* __restrict__ W0,
    const unsigned short* __restrict__ W1, const unsigned short* __restrict__ W2,
    const float* __restrict__ b0, const float* __restrict__ b1,
    const float* __restrict__ b2, unsigned short* __restrict__ O0,
    unsigned short* __restrict__ O1, unsigned short* __restrict__ O2) {
  __shared__ unsigned char a_lds[2][128 * 128];
  __shared__ unsigned char b_lds[2][128 * 128];
  const int tid = threadIdx.x;
  const int w = tid >> 6, l = tid & 63, lr = l & 15, hi = l >> 4;
  // decode XCD-affinity mapping
  const int bid = blockIdx.x;
  const int xcd = bid & 7;
  const int rest = bid >> 3;            // = (m0>>3)*12 + j
  const int j = rest % 12;
  const int mhi = rest / 12;            // m0 >> 3
  const int which = j >> 2;
  const unsigned short* W = which == 0 ? W0 : (which == 1 ? W1 : W2);
  const float* bias = which == 0 ? b0 : (which == 1 ? b1 : b2);
  unsigned short* out = which == 0 ? O0 : (which == 1 ? O1 : O2);
  const float oscale = which == 0 ? 0.044194173824159216f : 1.0f;
  const int m0 = ((mhi << 3) | xcd) * 128;
  const int n0 = (j & 3) * 128;
  const int wm = (w >> 1) * 64, wn = (w & 1) * 64;
  const int srow = l >> 3, gchunk = (l & 7) ^ (srow & 7);

  f32x4 acc[4][4];
#pragma unroll
  for (int mt = 0; mt < 4; ++mt)
#pragma unroll
    for (int nt = 0; nt < 4; ++nt) acc[mt][nt] = (f32x4){0.f, 0.f, 0.f, 0.f};

  const unsigned short* ga = X + (size_t)(m0 + w * 32 + srow) * DD + gchunk * 8;
  const unsigned short* gb = W + (size_t)(n0 + w * 32 + srow) * DD + gchunk * 8;

  for (int k0 = 0; k0 < DD; k0 += 128) {
#pragma unroll
    for (int ii = 0; ii < 4; ++ii) {
      gld16(ga + (size_t)ii * 8 * DD + k0, &a_lds[0][(w * 4 + ii) * 1024]);
      gld16(gb + (size_t)ii * 8 * DD + k0, &b_lds[0][(w * 4 + ii) * 1024]);
      gld16(ga + (size_t)ii * 8 * DD + k0 + 64, &a_lds[1][(w * 4 + ii) * 1024]);
      gld16(gb + (size_t)ii * 8 * DD + k0 + 64, &b_lds[1][(w * 4 + ii) * 1024]);
    }
    __syncthreads();
#pragma unroll
    for (int hf = 0; hf < 2; ++hf) {
#pragma unroll
      for (int dkl = 0; dkl < 2; ++dkl) {
        const int gc = dkl * 4 + hi;
        bf16x8 af[4], bfr[4];
#pragma unroll
        for (int mt = 0; mt < 4; ++mt) {
          const int row = wm + mt * 16 + lr;
          af[mt] = *reinterpret_cast<const bf16x8*>(
              &a_lds[hf][row * 128 + ((gc ^ (row & 7)) * 16)]);
        }
#pragma unroll
        for (int nt = 0; nt < 4; ++nt) {
          const int row = wn + nt * 16 + lr;
          bfr[nt] = *reinterpret_cast<const bf16x8*>(
              &b_lds[hf][row * 128 + ((gc ^ (row & 7)) * 16)]);
        }
#pragma unroll
        for (int mt = 0; mt < 4; ++mt)
#pragma unroll
          for (int nt = 0; nt < 4; ++nt)
            acc[mt][nt] = mfma16(af[mt], bfr[nt], acc[mt][nt]);
      }
    }
    __syncthreads();
  }

#pragma unroll
  for (int nt = 0; nt < 4; ++nt) {
    const int col = n0 + wn + nt * 16 + lr;
    const float bv = bias[col];
#pragma unroll
    for (int mt = 0; mt < 4; ++mt)
#pragma unroll
      for (int r = 0; r < 4; ++r) {
        const int row = m0 + wm + mt * 16 + hi * 4 + r;
        out[(size_t)row * DD + col] = f2bf((acc[mt][nt][r] + bv) * oscale);
      }
  }
}

// ---------------- V gather+tiled-transpose ----------------
// VT2[b][kt64][cc][d][jj] = Vc[b][kt64*64 + cc*8 + jj][d]
__global__ void vtrans_kernel(const unsigned short* __restrict__ V,
                              const int* __restrict__ idx, const int* __restrict__ nbArr,
                              unsigned short* __restrict__ VT2) {
  __shared__ unsigned short t[64][72];
  const int b = blockIdx.z;
  const int kt = blockIdx.x;
  const int d0 = blockIdx.y * 64;
  const int tid = threadIdx.x;
  const int c = tid & 63, rg = tid >> 6;
  const int nb = nbArr[b];
#pragma unroll
  for (int i = 0; i < 16; ++i) {
    const int row = rg * 16 + i;
    const int s = kt * 64 + row;
    const int src = s < nb ? idx[b * SS + s] : 0;
    t[row][c] = V[((size_t)b * SS + src) * DD + d0 + c];
  }
  __syncthreads();
#pragma unroll
  for (int i = 0; i < 16; ++i) {
    const int ix = i * 256 + tid;
    const int jj = ix & 7;
    const int dl = (ix >> 3) & 63;
    const int cc = ix >> 9;
    VT2[(((size_t)(b * 32 + kt) * 8 + cc) * 512 + d0 + dl) * 8 + jj] =
        t[cc * 8 + jj][dl];
  }
}

// ---------------- flash attention: R8 structure + pbuf chunk-XOR swizzle -----
// pbuf element (row,col) stored at chunk (col>>3)^(row>>2) within the row
// (writer's row>>2 == its hi); read 16B at chunk hi^(lr>>2). Breaks the
// 8-way write conflict (rows 4 apart = 256B = same banks).
__global__ __launch_bounds__(256, 2) void attn_kernel(
    const unsigned short* __restrict__ Q, const unsigned short* __restrict__ K,
    const unsigned short* __restrict__ VT2, const int* __restrict__ idx,
    const int* __restrict__ nbArr, float* __restrict__ Out,
    float* __restrict__ Apart, float* __restrict__ mlpart) {
  __shared__ unsigned char k_lds[32 * 1024];      // swizzled K tile
  __shared__ unsigned char vt_lds[4 * 512 * 16];  // [cc][d][8 keys]
  __shared__ unsigned short pbuf[4][16][32];
  __shared__ int ids[1024];
  const int tid = threadIdx.x;
  const int w = tid >> 6, l = tid & 63, lr = l & 15, hi = l >> 4;
  const int bid = blockIdx.x;
  const int b = bid & 7;  // XCD-affinity
  const int qt = (bid >> 3) >> 1;
  const int sp = (bid >> 3) & 1;
  const int q0 = qt * 64 + w * 16;

  const int nb = nbArr[b];
  const int ntile = (nb + 31) >> 5;
  const int half = (ntile + 1) >> 1;
  const int lo = sp == 0 ? 0 : half;
  const int hi_t = sp == 0 ? half : ntile;
  const int ntl = hi_t - lo;

  const unsigned short* __restrict__ Qb = Q + (size_t)b * SS * DD;
  const unsigned short* __restrict__ Kb = K + (size_t)b * SS * DD;
  const unsigned short* __restrict__ Vb = VT2 + (size_t)b * SS * DD;
  const int* __restrict__ idxb = idx + b * SS;

  for (int j = tid; j < ntl * 32; j += 256) ids[j] = idxb[lo * 32 + j];

  bf16x8 qf[16];
#pragma unroll
  for (int dk = 0; dk < 16; ++dk)
    qf[dk] = *reinterpret_cast<const bf16x8*>(
        &Qb[(size_t)(q0 + lr) * DD + dk * 32 + hi * 8]);

  f32x4 oacc[32];
#pragma unroll
  for (int i = 0; i < 32; ++i) oacc[i] = (f32x4){0.f, 0.f, 0.f, 0.f};
  float mrow[4], lrow[4];
#pragma unroll
  for (int r = 0; r < 4; ++r) {
    mrow[r] = -10000.0f;
    lrow[r] = 0.0f;
  }

  __syncthreads();  // ids visible

  for (int t = lo; t < hi_t; ++t) {
    const int tr = t - lo;
    // ---- issue K loads first (oldest 8 per lane) ----
#pragma unroll
    for (int r = 0; r < 8; ++r) {
      const int row = w * 8 + r;
      const int src = ids[tr * 32 + row];
      const int ch = (l & 56) | ((l ^ row) & 7);
      gld16(Kb + (size_t)src * DD + ch * 8, &k_lds[row * 1024]);
    }
    // ---- then V loads (youngest 8 per lane) ----
    const size_t vbase = ((size_t)((t >> 1) * 8 + (t & 1) * 4 + w) * 512);
#pragma unroll
    for (int g = 0; g < 8; ++g)
      gld16(Vb + (vbase + g * 64 + l) * 8, &vt_lds[(w * 512 + g * 64) * 16]);

    // ---- K landed (V still in flight) ----
    asm volatile("s_waitcnt vmcnt(8)" ::: "memory");
    __builtin_amdgcn_s_barrier();

    // ---- S = Q @ K^T (32 keys); Q pre-scaled ----
    f32x4 sacc[2];
#pragma unroll
    for (int nt = 0; nt < 2; ++nt) sacc[nt] = (f32x4){0.f, 0.f, 0.f, 0.f};
    __builtin_amdgcn_s_setprio(1);
#pragma unroll
    for (int dk = 0; dk < 16; ++dk) {
#pragma unroll
      for (int nt = 0; nt < 2; ++nt) {
        const int row = nt * 16 + lr;
        const int c = dk * 4 + hi;
        bf16x8 bk = *reinterpret_cast<const bf16x8*>(
            &k_lds[row * 1024 + ((c & ~7) | ((c ^ row) & 7)) * 16]);
        sacc[nt] = mfma16(qf[dk], bk, sacc[nt]);
      }
    }
    __builtin_amdgcn_s_setprio(0);

    float s[2][4];
#pragma unroll
    for (int nt = 0; nt < 2; ++nt) {
      const int j = t * 32 + nt * 16 + lr;
      const bool ok = j < nb;
#pragma unroll
      for (int r = 0; r < 4; ++r)
        s[nt][r] = ok ? sacc[nt][r] : -10000.0f;
    }

    // ---- online softmax with defer-max (T13, THR=8) ----
    float mx[4];
    float need = -1e30f;
#pragma unroll
    for (int r = 0; r < 4; ++r) {
      float m2 = fmaxf(s[0][r], s[1][r]);
#pragma unroll
      for (int off = 1; off < 16; off <<= 1) m2 = fmaxf(m2, __shfl_xor(m2, off));
      mx[r] = m2;
      need = fmaxf(need, m2 - mrow[r]);
    }
    if (__any(need > 8.0f)) {
#pragma unroll
      for (int r = 0; r < 4; ++r) {
        const float mnew = fmaxf(mrow[r], mx[r]);
        const float alpha = __expf(mrow[r] - mnew);
        mrow[r] = mnew;
        lrow[r] *= alpha;
#pragma unroll
        for (int nt2 = 0; nt2 < 32; ++nt2) oacc[nt2][r] *= alpha;
      }
    }
    float rs[4] = {0.f, 0.f, 0.f, 0.f};
#pragma unroll
    for (int nt = 0; nt < 2; ++nt)
#pragma unroll
      for (int r = 0; r < 4; ++r) {
        float p = __expf(s[nt][r] - mrow[r]);
        s[nt][r] = p;
        rs[r] += p;
      }
#pragma unroll
    for (int r = 0; r < 4; ++r) {
      float tt = rs[r];
#pragma unroll
      for (int off = 1; off < 16; off <<= 1) tt += __shfl_xor(tt, off);
      lrow[r] += tt;
    }

    // ---- P relayout C->A via per-wave LDS (chunk-XOR swizzled) ----
#pragma unroll
    for (int nt = 0; nt < 2; ++nt)
#pragma unroll
      for (int r = 0; r < 4; ++r) {
        const int col = nt * 16 + lr;
        pbuf[w][hi * 4 + r][(((col >> 3) ^ hi) << 3) | (col & 7)] =
            f2bf(s[nt][r]);
      }
    bf16x8 pf = *reinterpret_cast<const bf16x8*>(
        &pbuf[w][lr][(hi ^ (lr >> 2)) << 3]);

    // ---- V landed for all waves ----
    asm volatile("s_waitcnt vmcnt(0)" ::: "memory");
    __builtin_amdgcn_s_barrier();

    // ---- O += P @ V from LDS ----
    __builtin_amdgcn_s_setprio(1);
#pragma unroll
    for (int nt2 = 0; nt2 < 32; ++nt2) {
      bf16x8 v0 = *reinterpret_cast<const bf16x8*>(
          &vt_lds[(hi * 512 + nt2 * 16 + lr) * 16]);
      oacc[nt2] = mfma16(pf, v0, oacc[nt2]);
    }
    __builtin_amdgcn_s_setprio(0);
    __syncthreads();  // all PV reads done before next tile's staging
  }

  float* Ap = sp == 0 ? Out : Apart;
#pragma unroll
  for (int nt2 = 0; nt2 < 32; ++nt2)
#pragma unroll
    for (int r = 0; r < 4; ++r)
      Ap[((size_t)b * SS + q0 + hi * 4 + r) * DD + nt2 * 16 + lr] = oacc[nt2][r];
  if (lr == 0) {
#pragma unroll
    for (int r = 0; r < 4; ++r) {
      const size_t row = (size_t)sp * MM + b * SS + q0 + hi * 4 + r;
      mlpart[row * 2 + 0] = mrow[r];
      mlpart[row * 2 + 1] = lrow[r];
    }
  }
}

// ---------------- combine: in-place merge split0 (in Out) + split1 (Apart) ----------------
__global__ void combine_kernel(float* __restrict__ Out, const float* __restrict__ Apart,
                               const float* __restrict__ mlpart) {
  const int gid = blockIdx.x * 256 + threadIdx.x;  // over MM*DD/4
  const int row = gid >> 7;
  const float m1 = mlpart[(size_t)row * 2 + 0];
  const float l1 = mlpart[(size_t)row * 2 + 1];
  const float m2 = mlpart[((size_t)MM + row) * 2 + 0];
  const float l2 = mlpart[((size_t)MM + row) * 2 + 1];
  const float m = fmaxf(m1, m2);
  const float w1 = __expf(m1 - m), w2 = __expf(m2 - m);
  const float inv = 1.0f / (w1 * l1 + w2 * l2);
  f32x4 a1 = reinterpret_cast<f32x4*>(Out)[gid];
  f32x4 a2 = reinterpret_cast<const f32x4*>(Apart)[gid];
  f32x4 o;
#pragma unroll
  for (int e = 0; e < 4; ++e) o[e] = (w1 * a1[e] + w2 * a2[e]) * inv;
  reinterpret_cast<f32x4*>(Out)[gid] = o;
}

extern "C" void kernel_launch(void* const* d_in, const int* in_sizes, int n_in,
                              void* d_out, int out_size, void* d_ws, size_t ws_size,
                              hipStream_t stream) {
  const float* x = (const float*)d_in[0];
  const int* mask = (const int*)d_in[1];
  const float* Wq = (const float*)d_in[2];
  const float* bq = (const float*)d_in[3];
  const float* Wk = (const float*)d_in[4];
  const float* bk = (const float*)d_in[5];
  const float* Wv = (const float*)d_in[6];
  const float* bv = (const float*)d_in[7];
  float* out = (float*)d_out;

  // ws layout (max ~82.4 MB, R4-proven):
  //   0-16   Qb          (live through attn)
  //   16-32  Kb          (live through attn)
  //   32-48  VT2b        (live through attn)
  //   48-64  Xb          (dead after qkv_gemm)
  //   64-80  Vb          (dead after vtrans)
  //   48-80  Apart       (split1 partial, 32 MB — aliases Xb+Vb, both dead)
  //   80-81.5 weights    (dead after qkv_gemm)
  //   82+    idx (64KB), nbArr, mlpart (256KB)
  char* ws = (char*)d_ws;
  const size_t MB = 1024 * 1024;
  unsigned short* Qb = (unsigned short*)(ws);
  unsigned short* Kb = (unsigned short*)(ws + 16 * MB);
  unsigned short* VT2b = (unsigned short*)(ws + 32 * MB);
  unsigned short* Xb = (unsigned short*)(ws + 48 * MB);
  unsigned short* Vb = (unsigned short*)(ws + 64 * MB);
  float* Apart = (float*)(ws + 48 * MB);
  unsigned short* Wqb = (unsigned short*)(ws + 80 * MB);
  unsigned short* Wkb = Wqb + 512 * 512;
  unsigned short* Wvb = Wkb + 512 * 512;
  int* idx = (int*)(ws + 82 * MB);
  int* nbArr = (int*)(ws + 82 * MB + 65536);
  float* mlpart = (float*)(ws + 82 * MB + 128 * 1024);

  prep_kernel<<<8968, 256, 0, stream>>>(x, Xb, Wq, Wk, Wv, Wqb, Wkb, Wvb, mask, idx,
                                        nbArr);

  qkv_gemm_kernel<<<1536, 256, 0, stream>>>(Xb, Wqb, Wkb, Wvb, bq, bk, bv, Qb, Kb, Vb);

  vtrans_kernel<<<dim3(SS / 64, DD / 64, BB), 256, 0, stream>>>(Vb, idx, nbArr, VT2b);

  attn_kernel<<<512, 256, 0, stream>>>(Qb, Kb, VT2b, idx, nbArr, out, Apart, mlpart);

  combine_kernel<<<(MM * DD / 4) / 256, 256, 0, stream>>>(out, Apart, mlpart);
}

// Round 12
// 223.905 us; speedup vs baseline: 1.0594x; 1.0188x over previous
//
#include <hip/hip_runtime.h>
#include <cstddef>

#define BB 8
#define SS 2048
#define DD 512
#define MM (BB * SS)

typedef __attribute__((ext_vector_type(8))) short bf16x8;
typedef __attribute__((ext_vector_type(4))) float f32x4;
typedef __attribute__((ext_vector_type(4))) unsigned short u16x4;

__device__ __forceinline__ f32x4 mfma16(bf16x8 a, bf16x8 b, f32x4 c) {
  return __builtin_amdgcn_mfma_f32_16x16x32_bf16(a, b, c, 0, 0, 0);
}
__device__ __forceinline__ unsigned short f2bf(float f) {
  unsigned int u = __float_as_uint(f);
  u += 0x7fffu + ((u >> 16) & 1u);
  return (unsigned short)(u >> 16);
}
__device__ __forceinline__ void gld16(const void* g, void* l) {
  __builtin_amdgcn_global_load_lds((const __attribute__((address_space(1))) void*)g,
                                   (__attribute__((address_space(3))) void*)l, 16, 0, 0);
}

// ---------------- merged prep: x->bf16 (8192 blocks), W3->bf16 (768), mask scan (8) ----
__global__ void prep_kernel(const float* __restrict__ x, unsigned short* __restrict__ Xb,
                            const float* __restrict__ Wq, const float* __restrict__ Wk,
                            const float* __restrict__ Wv, unsigned short* __restrict__ Wqb,
                            unsigned short* __restrict__ Wkb, unsigned short* __restrict__ Wvb,
                            const int* __restrict__ mask, int* __restrict__ idx,
                            int* __restrict__ nbArr) {
  __shared__ int part[256];
  const int bx = blockIdx.x;
  const int t = threadIdx.x;
  if (bx < 8192) {  // x conversion: 8192*256 f32x4 = MM*DD
    const int i = bx * 256 + t;
    f32x4 v = reinterpret_cast<const f32x4*>(x)[i];
    u16x4 o;
    o[0] = f2bf(v[0]);
    o[1] = f2bf(v[1]);
    o[2] = f2bf(v[2]);
    o[3] = f2bf(v[3]);
    reinterpret_cast<u16x4*>(Xb)[i] = o;
    return;
  }
  if (bx < 8960) {  // weights: 256 blocks per matrix
    const int k = bx - 8192;
    const int which = k >> 8;
    const float* s = which == 0 ? Wq : (which == 1 ? Wk : Wv);
    unsigned short* d = which == 0 ? Wqb : (which == 1 ? Wkb : Wvb);
    const int i = (k & 255) * 256 + t;
    f32x4 v = reinterpret_cast<const f32x4*>(s)[i];
    u16x4 o;
    o[0] = f2bf(v[0]);
    o[1] = f2bf(v[1]);
    o[2] = f2bf(v[2]);
    o[3] = f2bf(v[3]);
    reinterpret_cast<u16x4*>(d)[i] = o;
    return;
  }
  // ---- mask scan: active-key index list (tail zeroed), b = bx - 8960 ----
  const int b = bx - 8960;
  int m[8], c = 0;
#pragma unroll
  for (int e = 0; e < 8; ++e) {
    m[e] = mask[b * SS + t * 8 + e];
    c += (m[e] != 0);
  }
  int v = c;
  part[t] = v;
  __syncthreads();
  for (int off = 1; off < 256; off <<= 1) {
    int u = (t >= off) ? part[t - off] : 0;
    __syncthreads();
    v += u;
    part[t] = v;
    __syncthreads();
  }
  int base = v - c;
#pragma unroll
  for (int e = 0; e < 8; ++e)
    if (m[e]) idx[b * SS + base++] = t * 8 + e;
  const int nb = part[255];
  if (t == 255) nbArr[b] = nb;
  for (int j = nb + t; j < SS; j += 256) idx[b * SS + j] = 0;
}

// ---------------- fused QKV GEMM: 3 outputs per block (shared A tile) --------
// Block = (m0, n0); stages A once per K-64 step and B-tiles of ALL THREE
// weight matrices (LDS 16+48=64KB, 2 blocks/CU). 96 MFMAs/wave per barrier
// pair vs 64 before; A staged once instead of 3x; 512 blocks vs 1536.
// XCD affinity: 4 n-tiles sharing an A-panel sit 8 apart -> same XCD.
// Q output pre-scaled by 1/sqrt(512).
__global__ __launch_bounds__(256, 2) void qkv_gemm_kernel(
    const unsigned short* __restrict__ X, const unsigned short* __restrict__ W0,
    const unsigned short* __restrict__ W1, const unsigned short* __restrict__ W2,
    const float* __restrict__ b0, const float* __restrict__ b1,
    const float* __restrict__ b2, unsigned short* __restrict__ O0,
    unsigned short* __restrict__ O1, unsigned short* __restrict__ O2) {
  __shared__ unsigned char a_lds[16 * 1024];
  __shared__ unsigned char b_lds[3][16 * 1024];
  const int tid = threadIdx.x;
  const int w = tid >> 6, l = tid & 63, lr = l & 15, hi = l >> 4;
  const int bid = blockIdx.x;
  const int xcd = bid & 7;
  const int q = bid >> 3;       // [0,64)
  const int nI = q & 3;         // n-tile
  const int mhi = q >> 2;       // [0,16)
  const int m0 = (mhi * 8 + xcd) * 128;
  const int n0 = nI * 128;
  const int wm = (w >> 1) * 64, wn = (w & 1) * 64;
  const int srow = l >> 3, gchunk = (l & 7) ^ (srow & 7);

  f32x4 acc[3][4][4];
#pragma unroll
  for (int mat = 0; mat < 3; ++mat)
#pragma unroll
    for (int mt = 0; mt < 4; ++mt)
#pragma unroll
      for (int nt = 0; nt < 4; ++nt) acc[mat][mt][nt] = (f32x4){0.f, 0.f, 0.f, 0.f};

  const unsigned short* ga = X + (size_t)(m0 + w * 32 + srow) * DD + gchunk * 8;
  const unsigned short* gb0 = W0 + (size_t)(n0 + w * 32 + srow) * DD + gchunk * 8;
  const unsigned short* gb1 = W1 + (size_t)(n0 + w * 32 + srow) * DD + gchunk * 8;
  const unsigned short* gb2 = W2 + (size_t)(n0 + w * 32 + srow) * DD + gchunk * 8;

  for (int k0 = 0; k0 < DD; k0 += 64) {
#pragma unroll
    for (int ii = 0; ii < 4; ++ii) {
      const int dst = (w * 4 + ii) * 1024;
      gld16(ga + (size_t)ii * 8 * DD + k0, &a_lds[dst]);
      gld16(gb0 + (size_t)ii * 8 * DD + k0, &b_lds[0][dst]);
      gld16(gb1 + (size_t)ii * 8 * DD + k0, &b_lds[1][dst]);
      gld16(gb2 + (size_t)ii * 8 * DD + k0, &b_lds[2][dst]);
    }
    __syncthreads();
#pragma unroll
    for (int dkl = 0; dkl < 2; ++dkl) {
      const int gc = dkl * 4 + hi;
      bf16x8 af[4];
#pragma unroll
      for (int mt = 0; mt < 4; ++mt) {
        const int row = wm + mt * 16 + lr;
        af[mt] = *reinterpret_cast<const bf16x8*>(
            &a_lds[row * 128 + ((gc ^ (row & 7)) * 16)]);
      }
#pragma unroll
      for (int mat = 0; mat < 3; ++mat) {
        bf16x8 bfr[4];
#pragma unroll
        for (int nt = 0; nt < 4; ++nt) {
          const int row = wn + nt * 16 + lr;
          bfr[nt] = *reinterpret_cast<const bf16x8*>(
              &b_lds[mat][row * 128 + ((gc ^ (row & 7)) * 16)]);
        }
#pragma unroll
        for (int mt = 0; mt < 4; ++mt)
#pragma unroll
          for (int nt = 0; nt < 4; ++nt)
            acc[mat][mt][nt] = mfma16(af[mt], bfr[nt], acc[mat][mt][nt]);
      }
    }
    __syncthreads();
  }

#pragma unroll
  for (int mat = 0; mat < 3; ++mat) {
    const float* bias = mat == 0 ? b0 : (mat == 1 ? b1 : b2);
    unsigned short* out = mat == 0 ? O0 : (mat == 1 ? O1 : O2);
    const float oscale = mat == 0 ? 0.044194173824159216f : 1.0f;
#pragma unroll
    for (int nt = 0; nt < 4; ++nt) {
      const int col = n0 + wn + nt * 16 + lr;
      const float bv = bias[col];
#pragma unroll
      for (int mt = 0; mt < 4; ++mt)
#pragma unroll
        for (int r = 0; r < 4; ++r) {
          const int row = m0 + wm + mt * 16 + hi * 4 + r;
          out[(size_t)row * DD + col] = f2bf((acc[mat][mt][nt][r] + bv) * oscale);
        }
    }
  }
}

// ---------------- V gather+tiled-transpose ----------------
// VT2[b][kt64][cc][d][jj] = Vc[b][kt64*64 + cc*8 + jj][d]
__global__ void vtrans_kernel(const unsigned short* __restrict__ V,
                              const int* __restrict__ idx, const int* __restrict__ nbArr,
                              unsigned short* __restrict__ VT2) {
  __shared__ unsigned short t[64][72];
  const int b = blockIdx.z;
  const int kt = blockIdx.x;
  const int d0 = blockIdx.y * 64;
  const int tid = threadIdx.x;
  const int c = tid & 63, rg = tid >> 6;
  const int nb = nbArr[b];
#pragma unroll
  for (int i = 0; i < 16; ++i) {
    const int row = rg * 16 + i;
    const int s = kt * 64 + row;
    const int src = s < nb ? idx[b * SS + s] : 0;
    t[row][c] = V[((size_t)b * SS + src) * DD + d0 + c];
  }
  __syncthreads();
#pragma unroll
  for (int i = 0; i < 16; ++i) {
    const int ix = i * 256 + tid;
    const int jj = ix & 7;
    const int dl = (ix >> 3) & 63;
    const int cc = ix >> 9;
    VT2[(((size_t)(b * 32 + kt) * 8 + cc) * 512 + d0 + dl) * 8 + jj] =
        t[cc * 8 + jj][dl];
  }
}

// ---------------- flash attention: R8 structure + pbuf chunk-XOR swizzle -----
// (R11-proven; attn structure declared converged)
__global__ __launch_bounds__(256, 2) void attn_kernel(
    const unsigned short* __restrict__ Q, const unsigned short* __restrict__ K,
    const unsigned short* __restrict__ VT2, const int* __restrict__ idx,
    const int* __restrict__ nbArr, float* __restrict__ Out,
    float* __restrict__ Apart, float* __restrict__ mlpart) {
  __shared__ unsigned char k_lds[32 * 1024];      // swizzled K tile
  __shared__ unsigned char vt_lds[4 * 512 * 16];  // [cc][d][8 keys]
  __shared__ unsigned short pbuf[4][16][32];
  __shared__ int ids[1024];
  const int tid = threadIdx.x;
  const int w = tid >> 6, l = tid & 63, lr = l & 15, hi = l >> 4;
  const int bid = blockIdx.x;
  const int b = bid & 7;  // XCD-affinity
  const int qt = (bid >> 3) >> 1;
  const int sp = (bid >> 3) & 1;
  const int q0 = qt * 64 + w * 16;

  const int nb = nbArr[b];
  const int ntile = (nb + 31) >> 5;
  const int half = (ntile + 1) >> 1;
  const int lo = sp == 0 ? 0 : half;
  const int hi_t = sp == 0 ? half : ntile;
  const int ntl = hi_t - lo;

  const unsigned short* __restrict__ Qb = Q + (size_t)b * SS * DD;
  const unsigned short* __restrict__ Kb = K + (size_t)b * SS * DD;
  const unsigned short* __restrict__ Vb = VT2 + (size_t)b * SS * DD;
  const int* __restrict__ idxb = idx + b * SS;

  for (int j = tid; j < ntl * 32; j += 256) ids[j] = idxb[lo * 32 + j];

  bf16x8 qf[16];
#pragma unroll
  for (int dk = 0; dk < 16; ++dk)
    qf[dk] = *reinterpret_cast<const bf16x8*>(
        &Qb[(size_t)(q0 + lr) * DD + dk * 32 + hi * 8]);

  f32x4 oacc[32];
#pragma unroll
  for (int i = 0; i < 32; ++i) oacc[i] = (f32x4){0.f, 0.f, 0.f, 0.f};
  float mrow[4], lrow[4];
#pragma unroll
  for (int r = 0; r < 4; ++r) {
    mrow[r] = -10000.0f;
    lrow[r] = 0.0f;
  }

  __syncthreads();  // ids visible

  for (int t = lo; t < hi_t; ++t) {
    const int tr = t - lo;
    // ---- issue K loads first (oldest 8 per lane) ----
#pragma unroll
    for (int r = 0; r < 8; ++r) {
      const int row = w * 8 + r;
      const int src = ids[tr * 32 + row];
      const int ch = (l & 56) | ((l ^ row) & 7);
      gld16(Kb + (size_t)src * DD + ch * 8, &k_lds[row * 1024]);
    }
    // ---- then V loads (youngest 8 per lane) ----
    const size_t vbase = ((size_t)((t >> 1) * 8 + (t & 1) * 4 + w) * 512);
#pragma unroll
    for (int g = 0; g < 8; ++g)
      gld16(Vb + (vbase + g * 64 + l) * 8, &vt_lds[(w * 512 + g * 64) * 16]);

    // ---- K landed (V still in flight) ----
    asm volatile("s_waitcnt vmcnt(8)" ::: "memory");
    __builtin_amdgcn_s_barrier();

    // ---- S = Q @ K^T (32 keys); Q pre-scaled ----
    f32x4 sacc[2];
#pragma unroll
    for (int nt = 0; nt < 2; ++nt) sacc[nt] = (f32x4){0.f, 0.f, 0.f, 0.f};
    __builtin_amdgcn_s_setprio(1);
#pragma unroll
    for (int dk = 0; dk < 16; ++dk) {
#pragma unroll
      for (int nt = 0; nt < 2; ++nt) {
        const int row = nt * 16 + lr;
        const int c = dk * 4 + hi;
        bf16x8 bk = *reinterpret_cast<const bf16x8*>(
            &k_lds[row * 1024 + ((c & ~7) | ((c ^ row) & 7)) * 16]);
        sacc[nt] = mfma16(qf[dk], bk, sacc[nt]);
      }
    }
    __builtin_amdgcn_s_setprio(0);

    float s[2][4];
#pragma unroll
    for (int nt = 0; nt < 2; ++nt) {
      const int j = t * 32 + nt * 16 + lr;
      const bool ok = j < nb;
#pragma unroll
      for (int r = 0; r < 4; ++r)
        s[nt][r] = ok ? sacc[nt][r] : -10000.0f;
    }

    // ---- online softmax with defer-max (T13, THR=8) ----
    float mx[4];
    float need = -1e30f;
#pragma unroll
    for (int r = 0; r < 4; ++r) {
      float m2 = fmaxf(s[0][r], s[1][r]);
#pragma unroll
      for (int off = 1; off < 16; off <<= 1) m2 = fmaxf(m2, __shfl_xor(m2, off));
      mx[r] = m2;
      need = fmaxf(need, m2 - mrow[r]);
    }
    if (__any(need > 8.0f)) {
#pragma unroll
      for (int r = 0; r < 4; ++r) {
        const float mnew = fmaxf(mrow[r], mx[r]);
        const float alpha = __expf(mrow[r] - mnew);
        mrow[r] = mnew;
        lrow[r] *= alpha;
#pragma unroll
        for (int nt2 = 0; nt2 < 32; ++nt2) oacc[nt2][r] *= alpha;
      }
    }
    float rs[4] = {0.f, 0.f, 0.f, 0.f};
#pragma unroll
    for (int nt = 0; nt < 2; ++nt)
#pragma unroll
      for (int r = 0; r < 4; ++r) {
        float p = __expf(s[nt][r] - mrow[r]);
        s[nt][r] = p;
        rs[r] += p;
      }
#pragma unroll
    for (int r = 0; r < 4; ++r) {
      float tt = rs[r];
#pragma unroll
      for (int off = 1; off < 16; off <<= 1) tt += __shfl_xor(tt, off);
      lrow[r] += tt;
    }

    // ---- P relayout C->A via per-wave LDS (chunk-XOR swizzled) ----
#pragma unroll
    for (int nt = 0; nt < 2; ++nt)
#pragma unroll
      for (int r = 0; r < 4; ++r) {
        const int col = nt * 16 + lr;
        pbuf[w][hi * 4 + r][(((col >> 3) ^ hi) << 3) | (col & 7)] =
            f2bf(s[nt][r]);
      }
    bf16x8 pf = *reinterpret_cast<const bf16x8*>(
        &pbuf[w][lr][(hi ^ (lr >> 2)) << 3]);

    // ---- V landed for all waves ----
    asm volatile("s_waitcnt vmcnt(0)" ::: "memory");
    __builtin_amdgcn_s_barrier();

    // ---- O += P @ V from LDS ----
    __builtin_amdgcn_s_setprio(1);
#pragma unroll
    for (int nt2 = 0; nt2 < 32; ++nt2) {
      bf16x8 v0 = *reinterpret_cast<const bf16x8*>(
          &vt_lds[(hi * 512 + nt2 * 16 + lr) * 16]);
      oacc[nt2] = mfma16(pf, v0, oacc[nt2]);
    }
    __builtin_amdgcn_s_setprio(0);
    __syncthreads();  // all PV reads done before next tile's staging
  }

  float* Ap = sp == 0 ? Out : Apart;
#pragma unroll
  for (int nt2 = 0; nt2 < 32; ++nt2)
#pragma unroll
    for (int r = 0; r < 4; ++r)
      Ap[((size_t)b * SS + q0 + hi * 4 + r) * DD + nt2 * 16 + lr] = oacc[nt2][r];
  if (lr == 0) {
#pragma unroll
    for (int r = 0; r < 4; ++r) {
      const size_t row = (size_t)sp * MM + b * SS + q0 + hi * 4 + r;
      mlpart[row * 2 + 0] = mrow[r];
      mlpart[row * 2 + 1] = lrow[r];
    }
  }
}

// ---------------- combine: in-place merge split0 (in Out) + split1 (Apart) ----------------
__global__ void combine_kernel(float* __restrict__ Out, const float* __restrict__ Apart,
                               const float* __restrict__ mlpart) {
  const int gid = blockIdx.x * 256 + threadIdx.x;  // over MM*DD/4
  const int row = gid >> 7;
  const float m1 = mlpart[(size_t)row * 2 + 0];
  const float l1 = mlpart[(size_t)row * 2 + 1];
  const float m2 = mlpart[((size_t)MM + row) * 2 + 0];
  const float l2 = mlpart[((size_t)MM + row) * 2 + 1];
  const float m = fmaxf(m1, m2);
  const float w1 = __expf(m1 - m), w2 = __expf(m2 - m);
  const float inv = 1.0f / (w1 * l1 + w2 * l2);
  f32x4 a1 = reinterpret_cast<f32x4*>(Out)[gid];
  f32x4 a2 = reinterpret_cast<const f32x4*>(Apart)[gid];
  f32x4 o;
#pragma unroll
  for (int e = 0; e < 4; ++e) o[e] = (w1 * a1[e] + w2 * a2[e]) * inv;
  reinterpret_cast<f32x4*>(Out)[gid] = o;
}

extern "C" void kernel_launch(void* const* d_in, const int* in_sizes, int n_in,
                              void* d_out, int out_size, void* d_ws, size_t ws_size,
                              hipStream_t stream) {
  const float* x = (const float*)d_in[0];
  const int* mask = (const int*)d_in[1];
  const float* Wq = (const float*)d_in[2];
  const float* bq = (const float*)d_in[3];
  const float* Wk = (const float*)d_in[4];
  const float* bk = (const float*)d_in[5];
  const float* Wv = (const float*)d_in[6];
  const float* bv = (const float*)d_in[7];
  float* out = (float*)d_out;

  // ws layout (max ~82.4 MB, R4-proven):
  //   0-16   Qb          (live through attn)
  //   16-32  Kb          (live through attn)
  //   32-48  VT2b        (live through attn)
  //   48-64  Xb          (dead after qkv_gemm)
  //   64-80  Vb          (dead after vtrans)
  //   48-80  Apart       (split1 partial, 32 MB — aliases Xb+Vb, both dead)
  //   80-81.5 weights    (dead after qkv_gemm)
  //   82+    idx (64KB), nbArr, mlpart (256KB)
  char* ws = (char*)d_ws;
  const size_t MB = 1024 * 1024;
  unsigned short* Qb = (unsigned short*)(ws);
  unsigned short* Kb = (unsigned short*)(ws + 16 * MB);
  unsigned short* VT2b = (unsigned short*)(ws + 32 * MB);
  unsigned short* Xb = (unsigned short*)(ws + 48 * MB);
  unsigned short* Vb = (unsigned short*)(ws + 64 * MB);
  float* Apart = (float*)(ws + 48 * MB);
  unsigned short* Wqb = (unsigned short*)(ws + 80 * MB);
  unsigned short* Wkb = Wqb + 512 * 512;
  unsigned short* Wvb = Wkb + 512 * 512;
  int* idx = (int*)(ws + 82 * MB);
  int* nbArr = (int*)(ws + 82 * MB + 65536);
  float* mlpart = (float*)(ws + 82 * MB + 128 * 1024);

  prep_kernel<<<8968, 256, 0, stream>>>(x, Xb, Wq, Wk, Wv, Wqb, Wkb, Wvb, mask, idx,
                                        nbArr);

  qkv_gemm_kernel<<<512, 256, 0, stream>>>(Xb, Wqb, Wkb, Wvb, bq, bk, bv, Qb, Kb, Vb);

  vtrans_kernel<<<dim3(SS / 64, DD / 64, BB), 256, 0, stream>>>(Vb, idx, nbArr, VT2b);

  attn_kernel<<<512, 256, 0, stream>>>(Qb, Kb, VT2b, idx, nbArr, out, Apart, mlpart);

  combine_kernel<<<(MM * DD / 4) / 256, 256, 0, stream>>>(out, Apart, mlpart);
}